// Round 5
// baseline (562.991 us; speedup 1.0000x reference)
//
#include <hip/hip_runtime.h>
#include <hip/hip_bf16.h>

typedef __bf16 bf16;
typedef __bf16 bf16x4 __attribute__((ext_vector_type(4)));
typedef __bf16 bf16x8 __attribute__((ext_vector_type(8)));
typedef float floatx4 __attribute__((ext_vector_type(4)));
typedef float float4v __attribute__((ext_vector_type(4)));

#define MFMA16(a, b, c) __builtin_amdgcn_mfma_f32_16x16x32_bf16(a, b, c, 0, 0, 0)

constexpr int B_ = 2, S_ = 2048, DIM_ = 1024, H_ = 16, HD_ = 64;
constexpr float SCALE_ = 0.125f;   // HD^-0.5
constexpr float EPS_ = 1e-8f;

// ---------------------------------------------------------------- helpers
__device__ __forceinline__ void gload_lds16(const bf16* g, bf16* l) {
    __builtin_amdgcn_global_load_lds(
        (const __attribute__((address_space(1))) void*)g,
        (__attribute__((address_space(3))) void*)l, 16, 0, 0);
}

// ---------------------------------------------------------------- f32 -> bf16
__global__ __launch_bounds__(256) void cvt_kernel(const float* __restrict__ in,
                                                  bf16* __restrict__ out, int n4) {
    int i = blockIdx.x * 256 + threadIdx.x;
    if (i >= n4) return;
    float4v v = ((const float4v*)in)[i];
    bf16x4 o;
    o[0] = (bf16)v[0]; o[1] = (bf16)v[1]; o[2] = (bf16)v[2]; o[3] = (bf16)v[3];
    ((bf16x4*)out)[i] = o;
}

// ---------------------------------------------------------------- GEMM C = A(MxK) * B(NxK)^T
template<int OUTF32, int BIASED>
__global__ __launch_bounds__(256) void gemm_bt(const bf16* __restrict__ A,
                                               const bf16* __restrict__ B,
                                               void* __restrict__ Cp,
                                               const float* __restrict__ bias,
                                               int M, int N, int K) {
    __shared__ bf16 As[128 * 64];
    __shared__ bf16 Bs[128 * 64];
    const int lane = threadIdx.x & 63, wid = threadIdx.x >> 6;
    const int colL = lane & 15, grp = lane >> 4;
    const int bm = blockIdx.y * 128, bn = blockIdx.x * 128;
    const int wr = wid >> 1, wc = wid & 1;

    floatx4 acc[4][4];
#pragma unroll
    for (int m = 0; m < 4; ++m)
#pragma unroll
        for (int n = 0; n < 4; ++n) acc[m][n] = (floatx4){0.f, 0.f, 0.f, 0.f};

    for (int k0 = 0; k0 < K; k0 += 64) {
#pragma unroll
        for (int i = 0; i < 4; ++i) {
            int c = wid * 256 + i * 64 + lane;
            int row = c >> 3, sub = c & 7;
            gload_lds16(A + (size_t)(bm + row) * K + k0 + sub * 8,
                        &As[(wid * 256 + i * 64) * 8]);
            gload_lds16(B + (size_t)(bn + row) * K + k0 + sub * 8,
                        &Bs[(wid * 256 + i * 64) * 8]);
        }
        __syncthreads();
#pragma unroll
        for (int ks = 0; ks < 2; ++ks) {
            bf16x8 af[4], bfr[4];
#pragma unroll
            for (int m = 0; m < 4; ++m)
                af[m] = *(const bf16x8*)(&As[(wr * 64 + m * 16 + colL) * 64 + ks * 32 + grp * 8]);
#pragma unroll
            for (int n = 0; n < 4; ++n)
                bfr[n] = *(const bf16x8*)(&Bs[(wc * 64 + n * 16 + colL) * 64 + ks * 32 + grp * 8]);
#pragma unroll
            for (int m = 0; m < 4; ++m)
#pragma unroll
                for (int n = 0; n < 4; ++n)
                    acc[m][n] = MFMA16(af[m], bfr[n], acc[m][n]);
        }
        __syncthreads();
    }

#pragma unroll
    for (int m = 0; m < 4; ++m)
#pragma unroll
        for (int n = 0; n < 4; ++n)
#pragma unroll
            for (int r = 0; r < 4; ++r) {
                int row = bm + wr * 64 + m * 16 + grp * 4 + r;
                int col = bn + wc * 64 + n * 16 + colL;
                float v = acc[m][n][r];
                if (BIASED) v += bias[col];
                if (OUTF32) ((float*)Cp)[(size_t)row * N + col] = v;
                else        ((bf16*)Cp)[(size_t)row * N + col] = (bf16)v;
            }
}

// ---------------------------------------------------------------- RoPE (+scale), (B,S,DIM-slice) -> (B,H,S,HD)
__global__ __launch_bounds__(256) void rope_kernel(const bf16* __restrict__ in,
                                                   const float* __restrict__ fr,
                                                   bf16* __restrict__ out,
                                                   int in_ld, float scale) {
    int tid = blockIdx.x * 256 + threadIdx.x;
    int j = tid & 7, h = (tid >> 3) & 15, s = (tid >> 7) & 2047, b = tid >> 18;
    bf16x8 x = *(const bf16x8*)(in + (size_t)(b * 2048 + s) * in_ld + h * 64 + j * 8);
    const float* f = fr + (size_t)(b * 2048 + s) * 64 + j * 4;
    bf16x8 o;
#pragma unroll
    for (int i = 0; i < 4; ++i) {
        float c = f[i], sn = f[32 + i];
        float x0 = (float)x[2 * i], x1 = (float)x[2 * i + 1];
        o[2 * i]     = (bf16)((x0 * c - x1 * sn) * scale);
        o[2 * i + 1] = (bf16)((x0 * sn + x1 * c) * scale);
    }
    *(bf16x8*)(out + ((size_t)(b * 16 + h) * 2048 + s) * 64 + j * 8) = o;
}

// ---------------------------------------------------------------- V transpose: KVp(B,S,2048) v-part -> Vt(B,H,HD,S)
__global__ __launch_bounds__(256) void vtrans_kernel(const bf16* __restrict__ KVp,
                                                     bf16* __restrict__ Vt) {
    int bid = blockIdx.x;
    int sb = bid & 31, h = (bid >> 5) & 15, b = bid >> 9;
    __shared__ bf16 tile[64][66];
    int tid = threadIdx.x;
#pragma unroll
    for (int i = 0; i < 2; ++i) {
        int c = tid + i * 256;
        int row = c >> 3, sub = c & 7;
        bf16x8 x = *(const bf16x8*)(KVp + (size_t)(b * 2048 + sb * 64 + row) * 2048
                                    + 1024 + h * 64 + sub * 8);
#pragma unroll
        for (int k = 0; k < 8; ++k) tile[row][sub * 8 + k] = x[k];
    }
    __syncthreads();
#pragma unroll
    for (int i = 0; i < 2; ++i) {
        int c = tid + i * 256;
        int drow = c >> 3, sub = c & 7;
        bf16x8 o;
#pragma unroll
        for (int k = 0; k < 8; ++k) o[k] = tile[sub * 8 + k][drow];
        *(bf16x8*)(Vt + ((size_t)(b * 16 + h) * 64 + drow) * 2048 + sb * 64 + sub * 8) = o;
    }
}

// ---------------------------------------------------------------- fused attention, two-phase, shift-free
// Block = (b,h,64 q rows), 4 waves x 16 q rows. K staged in LDS (dbuf, swizzled
// source); V direct from global (L2-hot, broadcast across waves). Phase 1: U + O.
// Phase 2: recompute logits, bounce f32 tile through wave-private LDS, store
// attn = e*p*invU with 256B-contiguous row segments.
__global__ __launch_bounds__(256, 4) void attn_fused(const bf16* __restrict__ Qr,
                                                     const bf16* __restrict__ Kr,
                                                     const bf16* __restrict__ Vt,
                                                     const float* __restrict__ mask,
                                                     const float* __restrict__ prior,
                                                     float* __restrict__ attn_out,
                                                     bf16* __restrict__ O) {
    __shared__ bf16 KB[2][4096];
    __shared__ float FS[4][1088];     // 16 rows x 68 f32 per wave; aliased as P (bf16[1024]) in phase 1

    const int tid = threadIdx.x;
    const int lane = tid & 63, wv = tid >> 6;
    const int colL = lane & 15, grp = lane >> 4;
    const int bidx = blockIdx.x;              // b*512 + h*32 + qb
    const int qb = bidx & 31, h = (bidx >> 5) & 15, b = bidx >> 9;
    const int bh = b * H_ + h;
    const int q0 = qb * 64 + wv * 16;

    const bf16* Qbase = Qr + ((size_t)bh * S_ + q0) * HD_;
    const bf16* Kbase = Kr + (size_t)bh * S_ * HD_;
    const bf16* Vbase = Vt + (size_t)bh * HD_ * S_;
    const float* Mrow = mask + ((size_t)b * S_ + q0 + colL) * S_;
    const float* Prow = prior + ((size_t)b * S_ + q0 + colL) * S_;

    bf16x8 qf0 = *(const bf16x8*)(Qbase + (size_t)colL * HD_ + grp * 8);
    bf16x8 qf1 = *(const bf16x8*)(Qbase + (size_t)colL * HD_ + 32 + grp * 8);

    bf16* P = (bf16*)FS[wv];
    const int swz = (colL & 7) << 3;
    const int c7 = colL & 7;

    auto stageK = [&](int buf, int k0) {
#pragma unroll
        for (int i = 0; i < 2; ++i) {
            int c = i * 256 + tid;
            int row = c >> 3, sub = c & 7;
            gload_lds16(Kbase + (size_t)(k0 + row) * HD_ + ((sub ^ (row & 7)) << 3),
                        &KB[buf][(c & ~63) << 3]);
        }
    };

    float ua = 0.f;
    floatx4 oT[4];
#pragma unroll
    for (int dt = 0; dt < 4; ++dt) oT[dt] = (floatx4){0.f, 0.f, 0.f, 0.f};

    // ---------------- phase 1 prologue
    stageK(0, 0);
    __syncthreads();

    // ---------------- phase 1: U + O accumulation
    for (int kt = 0; kt < 32; ++kt) {
        const int k0 = kt * 64;
        const int cur = kt & 1;

        // independent global loads first (so their waitcnt doesn't drain the stage)
        float4v mk[4], pr[4];
#pragma unroll
        for (int ct = 0; ct < 4; ++ct) {
            mk[ct] = *(const float4v*)(Mrow + k0 + ct * 16 + grp * 4);
            pr[ct] = *(const float4v*)(Prow + k0 + ct * 16 + grp * 4);
        }
        bf16x8 vf[2][4];
#pragma unroll
        for (int ks = 0; ks < 2; ++ks)
#pragma unroll
            for (int dt = 0; dt < 4; ++dt)
                vf[ks][dt] = *(const bf16x8*)(Vbase + (size_t)(dt * 16 + colL) * S_
                                              + k0 + ks * 32 + grp * 8);
        // next-tile K stage
        if (kt < 31) stageK(cur ^ 1, k0 + 64);

        // QK^T from LDS
        floatx4 s[4];
#pragma unroll
        for (int ct = 0; ct < 4; ++ct) {
            const int r8 = (ct * 16 + colL) * 8;
            bf16x8 a0 = *(const bf16x8*)&KB[cur][(r8 + (grp ^ c7)) * 8];
            bf16x8 a1 = *(const bf16x8*)&KB[cur][(r8 + (grp ^ 4 ^ c7)) * 8];
            floatx4 acc = (floatx4){0.f, 0.f, 0.f, 0.f};
            acc = MFMA16(a0, qf0, acc);
            acc = MFMA16(a1, qf1, acc);
            s[ct] = acc;
        }
        // t = exp(s+mask)*clip(prior)
#pragma unroll
        for (int ct = 0; ct < 4; ++ct) {
            bf16x4 pw;
#pragma unroll
            for (int r = 0; r < 4; ++r) {
                float e = __expf(s[ct][r] + mk[ct][r]);
                float tv = e * fmaxf(pr[ct][r], EPS_);
                ua += tv;
                pw[r] = (bf16)tv;
            }
            *(bf16x4*)&P[(colL * 64 + ct * 16 + grp * 4) ^ swz] = pw;
        }
        // PV
#pragma unroll
        for (int ks = 0; ks < 2; ++ks) {
            bf16x8 pb = *(const bf16x8*)&P[(colL * 64 + ks * 32 + grp * 8) ^ swz];
#pragma unroll
            for (int dt = 0; dt < 4; ++dt)
                oT[dt] = MFMA16(vf[ks][dt], pb, oT[dt]);
        }
        __syncthreads();
    }

    // ---------------- U reduce + O write
    ua += __shfl_xor(ua, 16, 64);
    ua += __shfl_xor(ua, 32, 64);
    const float iu = 1.0f / ua;
#pragma unroll
    for (int dt = 0; dt < 4; ++dt) {
        bf16x4 ow;
#pragma unroll
        for (int r = 0; r < 4; ++r) ow[r] = (bf16)(oT[dt][r] * iu);
        *(bf16x4*)(O + ((size_t)b * S_ + q0 + colL) * DIM_ + h * HD_ + dt * 16 + grp * 4) = ow;
    }

    // ---------------- phase 2 prologue
    stageK(0, 0);
    __syncthreads();

    // ---------------- phase 2: recompute, write attn = e*p*invU (256B segments)
    const float* Aout = attn_out + (size_t)bh * S_ * S_;
    for (int kt = 0; kt < 32; ++kt) {
        const int k0 = kt * 64;
        const int cur = kt & 1;

        float4v mk[4], pr[4];
#pragma unroll
        for (int ct = 0; ct < 4; ++ct) {
            mk[ct] = *(const float4v*)(Mrow + k0 + ct * 16 + grp * 4);
            pr[ct] = *(const float4v*)(Prow + k0 + ct * 16 + grp * 4);
        }
        if (kt < 31) stageK(cur ^ 1, k0 + 64);

        floatx4 s[4];
#pragma unroll
        for (int ct = 0; ct < 4; ++ct) {
            const int r8 = (ct * 16 + colL) * 8;
            bf16x8 a0 = *(const bf16x8*)&KB[cur][(r8 + (grp ^ c7)) * 8];
            bf16x8 a1 = *(const bf16x8*)&KB[cur][(r8 + (grp ^ 4 ^ c7)) * 8];
            floatx4 acc = (floatx4){0.f, 0.f, 0.f, 0.f};
            acc = MFMA16(a0, qf0, acc);
            acc = MFMA16(a1, qf1, acc);
            s[ct] = acc;
        }
        // stage f32 tile into wave-private LDS (row = q, col = k-in-tile)
#pragma unroll
        for (int ct = 0; ct < 4; ++ct) {
            float4v o;
#pragma unroll
            for (int r = 0; r < 4; ++r)
                o[r] = __expf(s[ct][r] + mk[ct][r]) * fmaxf(pr[ct][r], EPS_) * iu;
            *(float4v*)&FS[wv][colL * 68 + ct * 16 + grp * 4] = o;
        }
        // transposed read-out: 4 rows x 256B contiguous per instruction
#pragma unroll
        for (int it = 0; it < 4; ++it) {
            const int row = it * 4 + grp;
            float4v v = *(const float4v*)&FS[wv][row * 68 + colL * 4];
            *(float4v*)(Aout + (size_t)(q0 + row) * S_ + k0 + colL * 4) = v;
        }
        __syncthreads();
    }
}

// ---------------------------------------------------------------- launch
extern "C" void kernel_launch(void* const* d_in, const int* in_sizes, int n_in,
                              void* d_out, int out_size, void* d_ws, size_t ws_size,
                              hipStream_t stream) {
    const float* q_x   = (const float*)d_in[0];
    const float* kv_x  = (const float*)d_in[1];
    const float* q_fr  = (const float*)d_in[2];
    const float* k_fr  = (const float*)d_in[3];
    const float* maskp = (const float*)d_in[4];
    const float* prior = (const float*)d_in[5];
    const float* Wq    = (const float*)d_in[6];
    const float* Wkv   = (const float*)d_in[7];
    const float* Wproj = (const float*)d_in[8];
    const float* bproj = (const float*)d_in[9];

    float* out_x    = (float*)d_out;                       // (B,S,DIM)
    float* out_attn = out_x + (size_t)B_ * S_ * DIM_;      // (B,H,S,S)

    char* w = (char*)d_ws;
    bf16* qx_b  = (bf16*)(w + (size_t)0);          //  8 MiB
    bf16* kvx_b = (bf16*)(w + ((size_t)8  << 20)); //  8 MiB
    bf16* wq_b  = (bf16*)(w + ((size_t)16 << 20)); //  2 MiB
    bf16* wkv_b = (bf16*)(w + ((size_t)18 << 20)); //  4 MiB
    bf16* wpj_b = (bf16*)(w + ((size_t)22 << 20)); //  2 MiB
    bf16* qp    = (bf16*)(w + ((size_t)24 << 20)); //  8 MiB  (B,S,DIM)
    bf16* kvp   = (bf16*)(w + ((size_t)32 << 20)); // 16 MiB  (B,S,2*DIM)
    bf16* qr    = (bf16*)(w + ((size_t)48 << 20)); //  8 MiB  (B,H,S,HD)
    bf16* kr    = (bf16*)(w + ((size_t)56 << 20)); //  8 MiB
    bf16* vt    = (bf16*)(w + ((size_t)64 << 20)); //  8 MiB  (B,H,HD,S)
    bf16* ob    = (bf16*)(w + ((size_t)72 << 20)); //  8 MiB  (B,S,DIM)

    // f32 -> bf16 conversions
    cvt_kernel<<<4096, 256, 0, stream>>>(q_x,   qx_b,  1048576);
    cvt_kernel<<<4096, 256, 0, stream>>>(kv_x,  kvx_b, 1048576);
    cvt_kernel<<<1024, 256, 0, stream>>>(Wq,    wq_b,   262144);
    cvt_kernel<<<2048, 256, 0, stream>>>(Wkv,   wkv_b,  524288);
    cvt_kernel<<<1024, 256, 0, stream>>>(Wproj, wpj_b,  262144);

    // projections
    gemm_bt<0, 0><<<dim3(8, 32),  256, 0, stream>>>(qx_b,  wq_b,  qp,  nullptr, 4096, 1024, 1024);
    gemm_bt<0, 0><<<dim3(16, 32), 256, 0, stream>>>(kvx_b, wkv_b, kvp, nullptr, 4096, 2048, 1024);

    // RoPE + layout
    rope_kernel<<<2048, 256, 0, stream>>>(qp,  q_fr, qr, 1024, SCALE_);
    rope_kernel<<<2048, 256, 0, stream>>>(kvp, k_fr, kr, 2048, 1.0f);
    vtrans_kernel<<<1024, 256, 0, stream>>>(kvp, vt);

    // fused attention: O + attn in one kernel
    attn_fused<<<1024, 256, 0, stream>>>(qr, kr, vt, maskp, prior, out_attn, ob);

    // output projection
    gemm_bt<1, 1><<<dim3(8, 32), 256, 0, stream>>>(ob, wpj_b, out_x, bproj, 4096, 1024, 1024);
}

// Round 6
// 532.479 us; speedup vs baseline: 1.0573x; 1.0573x over previous
//
#include <hip/hip_runtime.h>
#include <hip/hip_bf16.h>

typedef __bf16 bf16;
typedef __bf16 bf16x4 __attribute__((ext_vector_type(4)));
typedef __bf16 bf16x8 __attribute__((ext_vector_type(8)));
typedef float floatx4 __attribute__((ext_vector_type(4)));
typedef float float4v __attribute__((ext_vector_type(4)));

#define MFMA16(a, b, c) __builtin_amdgcn_mfma_f32_16x16x32_bf16(a, b, c, 0, 0, 0)

constexpr int B_ = 2, S_ = 2048, DIM_ = 1024, H_ = 16, HD_ = 64;
constexpr float SCALE_ = 0.125f;   // HD^-0.5
constexpr float EPS_ = 1e-8f;

// ---------------------------------------------------------------- helpers
__device__ __forceinline__ void gload_lds16(const bf16* g, bf16* l) {
    __builtin_amdgcn_global_load_lds(
        (const __attribute__((address_space(1))) void*)g,
        (__attribute__((address_space(3))) void*)l, 16, 0, 0);
}

// ---------------------------------------------------------------- f32 -> bf16
__global__ __launch_bounds__(256) void cvt_kernel(const float* __restrict__ in,
                                                  bf16* __restrict__ out, int n4) {
    int i = blockIdx.x * 256 + threadIdx.x;
    if (i >= n4) return;
    float4v v = ((const float4v*)in)[i];
    bf16x4 o;
    o[0] = (bf16)v[0]; o[1] = (bf16)v[1]; o[2] = (bf16)v[2]; o[3] = (bf16)v[3];
    ((bf16x4*)out)[i] = o;
}

// ---------------------------------------------------------------- GEMM C = A(MxK) * B(NxK)^T
template<int OUTF32, int BIASED>
__global__ __launch_bounds__(256) void gemm_bt(const bf16* __restrict__ A,
                                               const bf16* __restrict__ B,
                                               void* __restrict__ Cp,
                                               const float* __restrict__ bias,
                                               int M, int N, int K) {
    __shared__ bf16 As[128 * 64];
    __shared__ bf16 Bs[128 * 64];
    const int lane = threadIdx.x & 63, wid = threadIdx.x >> 6;
    const int colL = lane & 15, grp = lane >> 4;
    const int bm = blockIdx.y * 128, bn = blockIdx.x * 128;
    const int wr = wid >> 1, wc = wid & 1;

    floatx4 acc[4][4];
#pragma unroll
    for (int m = 0; m < 4; ++m)
#pragma unroll
        for (int n = 0; n < 4; ++n) acc[m][n] = (floatx4){0.f, 0.f, 0.f, 0.f};

    for (int k0 = 0; k0 < K; k0 += 64) {
#pragma unroll
        for (int i = 0; i < 4; ++i) {
            int c = wid * 256 + i * 64 + lane;
            int row = c >> 3, sub = c & 7;
            gload_lds16(A + (size_t)(bm + row) * K + k0 + sub * 8,
                        &As[(wid * 256 + i * 64) * 8]);
            gload_lds16(B + (size_t)(bn + row) * K + k0 + sub * 8,
                        &Bs[(wid * 256 + i * 64) * 8]);
        }
        __syncthreads();
#pragma unroll
        for (int ks = 0; ks < 2; ++ks) {
            bf16x8 af[4], bfr[4];
#pragma unroll
            for (int m = 0; m < 4; ++m)
                af[m] = *(const bf16x8*)(&As[(wr * 64 + m * 16 + colL) * 64 + ks * 32 + grp * 8]);
#pragma unroll
            for (int n = 0; n < 4; ++n)
                bfr[n] = *(const bf16x8*)(&Bs[(wc * 64 + n * 16 + colL) * 64 + ks * 32 + grp * 8]);
#pragma unroll
            for (int m = 0; m < 4; ++m)
#pragma unroll
                for (int n = 0; n < 4; ++n)
                    acc[m][n] = MFMA16(af[m], bfr[n], acc[m][n]);
        }
        __syncthreads();
    }

#pragma unroll
    for (int m = 0; m < 4; ++m)
#pragma unroll
        for (int n = 0; n < 4; ++n)
#pragma unroll
            for (int r = 0; r < 4; ++r) {
                int row = bm + wr * 64 + m * 16 + grp * 4 + r;
                int col = bn + wc * 64 + n * 16 + colL;
                float v = acc[m][n][r];
                if (BIASED) v += bias[col];
                if (OUTF32) ((float*)Cp)[(size_t)row * N + col] = v;
                else        ((bf16*)Cp)[(size_t)row * N + col] = (bf16)v;
            }
}

// ---------------------------------------------------------------- RoPE (+scale), (B,S,DIM-slice) -> (B,H,S,HD)
__global__ __launch_bounds__(256) void rope_kernel(const bf16* __restrict__ in,
                                                   const float* __restrict__ fr,
                                                   bf16* __restrict__ out,
                                                   int in_ld, float scale) {
    int tid = blockIdx.x * 256 + threadIdx.x;
    int j = tid & 7, h = (tid >> 3) & 15, s = (tid >> 7) & 2047, b = tid >> 18;
    bf16x8 x = *(const bf16x8*)(in + (size_t)(b * 2048 + s) * in_ld + h * 64 + j * 8);
    const float* f = fr + (size_t)(b * 2048 + s) * 64 + j * 4;
    bf16x8 o;
#pragma unroll
    for (int i = 0; i < 4; ++i) {
        float c = f[i], sn = f[32 + i];
        float x0 = (float)x[2 * i], x1 = (float)x[2 * i + 1];
        o[2 * i]     = (bf16)((x0 * c - x1 * sn) * scale);
        o[2 * i + 1] = (bf16)((x0 * sn + x1 * c) * scale);
    }
    *(bf16x8*)(out + ((size_t)(b * 16 + h) * 2048 + s) * 64 + j * 8) = o;
}

// ---------------------------------------------------------------- V transpose: KVp(B,S,2048) v-part -> Vt(B,H,HD,S)
__global__ __launch_bounds__(256) void vtrans_kernel(const bf16* __restrict__ KVp,
                                                     bf16* __restrict__ Vt) {
    int bid = blockIdx.x;
    int sb = bid & 31, h = (bid >> 5) & 15, b = bid >> 9;
    __shared__ bf16 tile[64][66];
    int tid = threadIdx.x;
#pragma unroll
    for (int i = 0; i < 2; ++i) {
        int c = tid + i * 256;
        int row = c >> 3, sub = c & 7;
        bf16x8 x = *(const bf16x8*)(KVp + (size_t)(b * 2048 + sb * 64 + row) * 2048
                                    + 1024 + h * 64 + sub * 8);
#pragma unroll
        for (int k = 0; k < 8; ++k) tile[row][sub * 8 + k] = x[k];
    }
    __syncthreads();
#pragma unroll
    for (int i = 0; i < 2; ++i) {
        int c = tid + i * 256;
        int drow = c >> 3, sub = c & 7;
        bf16x8 o;
#pragma unroll
        for (int k = 0; k < 8; ++k) o[k] = tile[sub * 8 + k][drow];
        *(bf16x8*)(Vt + ((size_t)(b * 16 + h) * 64 + drow) * 2048 + sb * 64 + sub * 8) = o;
    }
}

// ---------------------------------------------------------------- fused attention, two-phase, shift-free
// Block = (b,h,64 q rows), 4 waves x 16 q rows. K,V staged in LDS (dbuf, swizzled
// source). mask/prior register-prefetched one tile ahead. XCD-aware block swizzle:
// all 16 heads of a (b,qb) pair co-resident on ONE XCD so mask/prior lines are
// fetched into one L2 once and served 16x from L2 instead of 16x from L3.
__global__ __launch_bounds__(256) void attn_fused(const bf16* __restrict__ Qr,
                                                  const bf16* __restrict__ Kr,
                                                  const bf16* __restrict__ Vt,
                                                  const float* __restrict__ mask,
                                                  const float* __restrict__ prior,
                                                  float* __restrict__ attn_out,
                                                  bf16* __restrict__ O) {
    __shared__ bf16 KB[2][4096];
    __shared__ bf16 VB[2][4096];
    __shared__ bf16 plds[4][1024];

    const int tid = threadIdx.x;
    const int lane = tid & 63, wv = tid >> 6;
    const int colL = lane & 15, grp = lane >> 4;
    // XCD swizzle: n%8 = XCD. Pair p=(b,qb) pinned to XCD p%8; 16 h's contiguous.
    const int n = blockIdx.x;
    const int x = n & 7, j = n >> 3;
    const int h = j & 15;
    const int pp = (j >> 4) * 8 + x;          // pair index 0..63
    const int b = pp >> 5, qb = pp & 31;
    const int bh = b * H_ + h;
    const int q0 = qb * 64 + wv * 16;

    const bf16* Qbase = Qr + ((size_t)bh * S_ + q0) * HD_;
    const bf16* Kbase = Kr + (size_t)bh * S_ * HD_;
    const bf16* Vbase = Vt + (size_t)bh * HD_ * S_;
    const float* Mrow = mask + ((size_t)b * S_ + q0 + colL) * S_;
    const float* Prow = prior + ((size_t)b * S_ + q0 + colL) * S_;

    bf16x8 qf0 = *(const bf16x8*)(Qbase + (size_t)colL * HD_ + grp * 8);
    bf16x8 qf1 = *(const bf16x8*)(Qbase + (size_t)colL * HD_ + 32 + grp * 8);

    bf16* P = plds[wv];
    const int swz = (colL & 7) << 3;
    const int c7 = colL & 7;

    auto stageK = [&](int buf, int k0) {
#pragma unroll
        for (int i = 0; i < 2; ++i) {
            int c = i * 256 + tid;
            int row = c >> 3, sub = c & 7;
            gload_lds16(Kbase + (size_t)(k0 + row) * HD_ + ((sub ^ (row & 7)) << 3),
                        &KB[buf][(c & ~63) << 3]);
        }
    };
    auto stageV = [&](int buf, int k0) {
#pragma unroll
        for (int i = 0; i < 2; ++i) {
            int c = i * 256 + tid;
            int row = c >> 3, sub = c & 7;
            gload_lds16(Vbase + (size_t)row * S_ + k0 + ((sub ^ (row & 7)) << 3),
                        &VB[buf][(c & ~63) << 3]);
        }
    };

    float ua = 0.f;
    floatx4 oT[4];
#pragma unroll
    for (int dt = 0; dt < 4; ++dt) oT[dt] = (floatx4){0.f, 0.f, 0.f, 0.f};

    float4v mk[4], pr[4];

    // ---------------- phase 1 prologue
    stageK(0, 0);
    stageV(0, 0);
#pragma unroll
    for (int ct = 0; ct < 4; ++ct) {
        mk[ct] = *(const float4v*)(Mrow + ct * 16 + grp * 4);
        pr[ct] = *(const float4v*)(Prow + ct * 16 + grp * 4);
    }
    __syncthreads();

    // ---------------- phase 1: U + O accumulation
    for (int kt = 0; kt < 32; ++kt) {
        const int k0 = kt * 64;
        const int cur = kt & 1;

        // current-tile copies; prefetch next tile's mask/prior (full tile of cover)
        float4v cmk[4], cpr[4];
#pragma unroll
        for (int ct = 0; ct < 4; ++ct) { cmk[ct] = mk[ct]; cpr[ct] = pr[ct]; }
        if (kt < 31) {
#pragma unroll
            for (int ct = 0; ct < 4; ++ct) {
                mk[ct] = *(const float4v*)(Mrow + k0 + 64 + ct * 16 + grp * 4);
                pr[ct] = *(const float4v*)(Prow + k0 + 64 + ct * 16 + grp * 4);
            }
            stageK(cur ^ 1, k0 + 64);
            stageV(cur ^ 1, k0 + 64);
        }

        // QK^T from LDS
        floatx4 s[4];
#pragma unroll
        for (int ct = 0; ct < 4; ++ct) {
            const int r8 = (ct * 16 + colL) * 8;
            bf16x8 a0 = *(const bf16x8*)&KB[cur][(r8 + (grp ^ c7)) * 8];
            bf16x8 a1 = *(const bf16x8*)&KB[cur][(r8 + (grp ^ 4 ^ c7)) * 8];
            floatx4 acc = (floatx4){0.f, 0.f, 0.f, 0.f};
            acc = MFMA16(a0, qf0, acc);
            acc = MFMA16(a1, qf1, acc);
            s[ct] = acc;
        }
        // t = exp(s+mask)*clip(prior)
#pragma unroll
        for (int ct = 0; ct < 4; ++ct) {
            bf16x4 pw;
#pragma unroll
            for (int r = 0; r < 4; ++r) {
                float e = __expf(s[ct][r] + cmk[ct][r]);
                float tv = e * fmaxf(cpr[ct][r], EPS_);
                ua += tv;
                pw[r] = (bf16)tv;
            }
            *(bf16x4*)&P[(colL * 64 + ct * 16 + grp * 4) ^ swz] = pw;
        }
        // PV from LDS V
#pragma unroll
        for (int ks = 0; ks < 2; ++ks) {
            bf16x8 pb = *(const bf16x8*)&P[(colL * 64 + ks * 32 + grp * 8) ^ swz];
#pragma unroll
            for (int dt = 0; dt < 4; ++dt) {
                const int r8 = (dt * 16 + colL) * 8;
                bf16x8 vf = *(const bf16x8*)&VB[cur][(r8 + ((ks * 4 + grp) ^ c7)) * 8];
                oT[dt] = MFMA16(vf, pb, oT[dt]);
            }
        }
        __syncthreads();
    }

    // ---------------- U reduce + O write
    ua += __shfl_xor(ua, 16, 64);
    ua += __shfl_xor(ua, 32, 64);
    const float iu = 1.0f / ua;
#pragma unroll
    for (int dt = 0; dt < 4; ++dt) {
        bf16x4 ow;
#pragma unroll
        for (int r = 0; r < 4; ++r) ow[r] = (bf16)(oT[dt][r] * iu);
        *(bf16x4*)(O + ((size_t)b * S_ + q0 + colL) * DIM_ + h * HD_ + dt * 16 + grp * 4) = ow;
    }

    // ---------------- phase 2 prologue
    stageK(0, 0);
#pragma unroll
    for (int ct = 0; ct < 4; ++ct) {
        mk[ct] = *(const float4v*)(Mrow + ct * 16 + grp * 4);
        pr[ct] = *(const float4v*)(Prow + ct * 16 + grp * 4);
    }
    __syncthreads();

    // ---------------- phase 2: recompute, write attn = e*p*invU
    float* Arow = attn_out + ((size_t)bh * S_ + q0 + colL) * S_;
    for (int kt = 0; kt < 32; ++kt) {
        const int k0 = kt * 64;
        const int cur = kt & 1;

        float4v cmk[4], cpr[4];
#pragma unroll
        for (int ct = 0; ct < 4; ++ct) { cmk[ct] = mk[ct]; cpr[ct] = pr[ct]; }
        if (kt < 31) {
#pragma unroll
            for (int ct = 0; ct < 4; ++ct) {
                mk[ct] = *(const float4v*)(Mrow + k0 + 64 + ct * 16 + grp * 4);
                pr[ct] = *(const float4v*)(Prow + k0 + 64 + ct * 16 + grp * 4);
            }
            stageK(cur ^ 1, k0 + 64);
        }

        floatx4 s[4];
#pragma unroll
        for (int ct = 0; ct < 4; ++ct) {
            const int r8 = (ct * 16 + colL) * 8;
            bf16x8 a0 = *(const bf16x8*)&KB[cur][(r8 + (grp ^ c7)) * 8];
            bf16x8 a1 = *(const bf16x8*)&KB[cur][(r8 + (grp ^ 4 ^ c7)) * 8];
            floatx4 acc = (floatx4){0.f, 0.f, 0.f, 0.f};
            acc = MFMA16(a0, qf0, acc);
            acc = MFMA16(a1, qf1, acc);
            s[ct] = acc;
        }
#pragma unroll
        for (int ct = 0; ct < 4; ++ct) {
            float4v o;
#pragma unroll
            for (int r = 0; r < 4; ++r)
                o[r] = __expf(s[ct][r] + cmk[ct][r]) * fmaxf(cpr[ct][r], EPS_) * iu;
            *(float4v*)(Arow + k0 + ct * 16 + grp * 4) = o;
        }
        __syncthreads();
    }
}

// ---------------------------------------------------------------- launch
extern "C" void kernel_launch(void* const* d_in, const int* in_sizes, int n_in,
                              void* d_out, int out_size, void* d_ws, size_t ws_size,
                              hipStream_t stream) {
    const float* q_x   = (const float*)d_in[0];
    const float* kv_x  = (const float*)d_in[1];
    const float* q_fr  = (const float*)d_in[2];
    const float* k_fr  = (const float*)d_in[3];
    const float* maskp = (const float*)d_in[4];
    const float* prior = (const float*)d_in[5];
    const float* Wq    = (const float*)d_in[6];
    const float* Wkv   = (const float*)d_in[7];
    const float* Wproj = (const float*)d_in[8];
    const float* bproj = (const float*)d_in[9];

    float* out_x    = (float*)d_out;                       // (B,S,DIM)
    float* out_attn = out_x + (size_t)B_ * S_ * DIM_;      // (B,H,S,S)

    char* w = (char*)d_ws;
    bf16* qx_b  = (bf16*)(w + (size_t)0);          //  8 MiB
    bf16* kvx_b = (bf16*)(w + ((size_t)8  << 20)); //  8 MiB
    bf16* wq_b  = (bf16*)(w + ((size_t)16 << 20)); //  2 MiB
    bf16* wkv_b = (bf16*)(w + ((size_t)18 << 20)); //  4 MiB
    bf16* wpj_b = (bf16*)(w + ((size_t)22 << 20)); //  2 MiB
    bf16* qp    = (bf16*)(w + ((size_t)24 << 20)); //  8 MiB  (B,S,DIM)
    bf16* kvp   = (bf16*)(w + ((size_t)32 << 20)); // 16 MiB  (B,S,2*DIM)
    bf16* qr    = (bf16*)(w + ((size_t)48 << 20)); //  8 MiB  (B,H,S,HD)
    bf16* kr    = (bf16*)(w + ((size_t)56 << 20)); //  8 MiB
    bf16* vt    = (bf16*)(w + ((size_t)64 << 20)); //  8 MiB  (B,H,HD,S)
    bf16* ob    = (bf16*)(w + ((size_t)72 << 20)); //  8 MiB  (B,S,DIM)

    // f32 -> bf16 conversions
    cvt_kernel<<<4096, 256, 0, stream>>>(q_x,   qx_b,  1048576);
    cvt_kernel<<<4096, 256, 0, stream>>>(kv_x,  kvx_b, 1048576);
    cvt_kernel<<<1024, 256, 0, stream>>>(Wq,    wq_b,   262144);
    cvt_kernel<<<2048, 256, 0, stream>>>(Wkv,   wkv_b,  524288);
    cvt_kernel<<<1024, 256, 0, stream>>>(Wproj, wpj_b,  262144);

    // projections
    gemm_bt<0, 0><<<dim3(8, 32),  256, 0, stream>>>(qx_b,  wq_b,  qp,  nullptr, 4096, 1024, 1024);
    gemm_bt<0, 0><<<dim3(16, 32), 256, 0, stream>>>(kvx_b, wkv_b, kvp, nullptr, 4096, 2048, 1024);

    // RoPE + layout
    rope_kernel<<<2048, 256, 0, stream>>>(qp,  q_fr, qr, 1024, SCALE_);
    rope_kernel<<<2048, 256, 0, stream>>>(kvp, k_fr, kr, 2048, 1.0f);
    vtrans_kernel<<<1024, 256, 0, stream>>>(kvp, vt);

    // fused attention: O + attn in one kernel (XCD-swizzled grid)
    attn_fused<<<1024, 256, 0, stream>>>(qr, kr, vt, maskp, prior, out_attn, ob);

    // output projection
    gemm_bt<1, 1><<<dim3(8, 32), 256, 0, stream>>>(ob, wpj_b, out_x, bproj, 4096, 1024, 1024);
}

// Round 7
// 417.359 us; speedup vs baseline: 1.3489x; 1.2758x over previous
//
#include <hip/hip_runtime.h>
#include <hip/hip_bf16.h>

typedef __bf16 bf16;
typedef __bf16 bf16x4 __attribute__((ext_vector_type(4)));
typedef __bf16 bf16x8 __attribute__((ext_vector_type(8)));
typedef float floatx4 __attribute__((ext_vector_type(4)));
typedef float float4v __attribute__((ext_vector_type(4)));

#define MFMA16(a, b, c) __builtin_amdgcn_mfma_f32_16x16x32_bf16(a, b, c, 0, 0, 0)

constexpr int B_ = 2, S_ = 2048, DIM_ = 1024, H_ = 16, HD_ = 64;
constexpr float SCALE_ = 0.125f;   // HD^-0.5
constexpr float EPS_ = 1e-8f;

// ---------------------------------------------------------------- helpers
__device__ __forceinline__ void gload_lds16(const void* g, void* l) {
    __builtin_amdgcn_global_load_lds(
        (const __attribute__((address_space(1))) void*)g,
        (__attribute__((address_space(3))) void*)l, 16, 0, 0);
}

// ---------------------------------------------------------------- f32 -> bf16
__global__ __launch_bounds__(256) void cvt_kernel(const float* __restrict__ in,
                                                  bf16* __restrict__ out, int n4) {
    int i = blockIdx.x * 256 + threadIdx.x;
    if (i >= n4) return;
    float4v v = ((const float4v*)in)[i];
    bf16x4 o;
    o[0] = (bf16)v[0]; o[1] = (bf16)v[1]; o[2] = (bf16)v[2]; o[3] = (bf16)v[3];
    ((bf16x4*)out)[i] = o;
}

// ---------------------------------------------------------------- lp = mask + ln(clip(prior))
__global__ __launch_bounds__(256) void lp_kernel(const float* __restrict__ mask,
                                                 const float* __restrict__ prior,
                                                 float* __restrict__ lp, int n4) {
    int i = blockIdx.x * 256 + threadIdx.x;
    if (i >= n4) return;
    float4v m = ((const float4v*)mask)[i];
    float4v p = ((const float4v*)prior)[i];
    float4v o;
#pragma unroll
    for (int j = 0; j < 4; ++j) o[j] = m[j] + __logf(fmaxf(p[j], EPS_));
    ((float4v*)lp)[i] = o;
}

// ---------------------------------------------------------------- GEMM C = A(MxK) * B(NxK)^T
template<int OUTF32, int BIASED>
__global__ __launch_bounds__(256) void gemm_bt(const bf16* __restrict__ A,
                                               const bf16* __restrict__ B,
                                               void* __restrict__ Cp,
                                               const float* __restrict__ bias,
                                               int M, int N, int K) {
    __shared__ bf16 As[128 * 64];
    __shared__ bf16 Bs[128 * 64];
    const int lane = threadIdx.x & 63, wid = threadIdx.x >> 6;
    const int colL = lane & 15, grp = lane >> 4;
    const int bm = blockIdx.y * 128, bn = blockIdx.x * 128;
    const int wr = wid >> 1, wc = wid & 1;

    floatx4 acc[4][4];
#pragma unroll
    for (int m = 0; m < 4; ++m)
#pragma unroll
        for (int n = 0; n < 4; ++n) acc[m][n] = (floatx4){0.f, 0.f, 0.f, 0.f};

    for (int k0 = 0; k0 < K; k0 += 64) {
#pragma unroll
        for (int i = 0; i < 4; ++i) {
            int c = wid * 256 + i * 64 + lane;
            int row = c >> 3, sub = c & 7;
            gload_lds16(A + (size_t)(bm + row) * K + k0 + sub * 8,
                        &As[(wid * 256 + i * 64) * 8]);
            gload_lds16(B + (size_t)(bn + row) * K + k0 + sub * 8,
                        &Bs[(wid * 256 + i * 64) * 8]);
        }
        __syncthreads();
#pragma unroll
        for (int ks = 0; ks < 2; ++ks) {
            bf16x8 af[4], bfr[4];
#pragma unroll
            for (int m = 0; m < 4; ++m)
                af[m] = *(const bf16x8*)(&As[(wr * 64 + m * 16 + colL) * 64 + ks * 32 + grp * 8]);
#pragma unroll
            for (int n = 0; n < 4; ++n)
                bfr[n] = *(const bf16x8*)(&Bs[(wc * 64 + n * 16 + colL) * 64 + ks * 32 + grp * 8]);
#pragma unroll
            for (int m = 0; m < 4; ++m)
#pragma unroll
                for (int n = 0; n < 4; ++n)
                    acc[m][n] = MFMA16(af[m], bfr[n], acc[m][n]);
        }
        __syncthreads();
    }

#pragma unroll
    for (int m = 0; m < 4; ++m)
#pragma unroll
        for (int n = 0; n < 4; ++n)
#pragma unroll
            for (int r = 0; r < 4; ++r) {
                int row = bm + wr * 64 + m * 16 + grp * 4 + r;
                int col = bn + wc * 64 + n * 16 + colL;
                float v = acc[m][n][r];
                if (BIASED) v += bias[col];
                if (OUTF32) ((float*)Cp)[(size_t)row * N + col] = v;
                else        ((bf16*)Cp)[(size_t)row * N + col] = (bf16)v;
            }
}

// ---------------------------------------------------------------- RoPE (+scale), (B,S,DIM-slice) -> (B,H,S,HD)
__global__ __launch_bounds__(256) void rope_kernel(const bf16* __restrict__ in,
                                                   const float* __restrict__ fr,
                                                   bf16* __restrict__ out,
                                                   int in_ld, float scale) {
    int tid = blockIdx.x * 256 + threadIdx.x;
    int j = tid & 7, h = (tid >> 3) & 15, s = (tid >> 7) & 2047, b = tid >> 18;
    bf16x8 x = *(const bf16x8*)(in + (size_t)(b * 2048 + s) * in_ld + h * 64 + j * 8);
    const float* f = fr + (size_t)(b * 2048 + s) * 64 + j * 4;
    bf16x8 o;
#pragma unroll
    for (int i = 0; i < 4; ++i) {
        float c = f[i], sn = f[32 + i];
        float x0 = (float)x[2 * i], x1 = (float)x[2 * i + 1];
        o[2 * i]     = (bf16)((x0 * c - x1 * sn) * scale);
        o[2 * i + 1] = (bf16)((x0 * sn + x1 * c) * scale);
    }
    *(bf16x8*)(out + ((size_t)(b * 16 + h) * 2048 + s) * 64 + j * 8) = o;
}

// ---------------------------------------------------------------- V transpose: KVp(B,S,2048) v-part -> Vt(B,H,HD,S)
__global__ __launch_bounds__(256) void vtrans_kernel(const bf16* __restrict__ KVp,
                                                     bf16* __restrict__ Vt) {
    int bid = blockIdx.x;
    int sb = bid & 31, h = (bid >> 5) & 15, b = bid >> 9;
    __shared__ bf16 tile[64][66];
    int tid = threadIdx.x;
#pragma unroll
    for (int i = 0; i < 2; ++i) {
        int c = tid + i * 256;
        int row = c >> 3, sub = c & 7;
        bf16x8 x = *(const bf16x8*)(KVp + (size_t)(b * 2048 + sb * 64 + row) * 2048
                                    + 1024 + h * 64 + sub * 8);
#pragma unroll
        for (int k = 0; k < 8; ++k) tile[row][sub * 8 + k] = x[k];
    }
    __syncthreads();
#pragma unroll
    for (int i = 0; i < 2; ++i) {
        int c = tid + i * 256;
        int drow = c >> 3, sub = c & 7;
        bf16x8 o;
#pragma unroll
        for (int k = 0; k < 8; ++k) o[k] = tile[sub * 8 + k][drow];
        *(bf16x8*)(Vt + ((size_t)(b * 16 + h) * 64 + drow) * 2048 + sb * 64 + sub * 8) = o;
    }
}

// ---------------------------------------------------------------- fused attention, two-phase, shift-free
// Block = (b,h,64 q rows), 4 waves x 16 q rows. K, V, AND the f32 lp-tile all
// staged in LDS via coalesced global_load_lds (dbuf, inverse-swizzled source).
// Phase 1: U + O accumulation. Phase 2: recompute logits, bounce f32 output tile
// through wave-private LDS (aliased over V/P space), 256B-contiguous stores.
__global__ __launch_bounds__(256) void attn_fused(const bf16* __restrict__ Qr,
                                                  const bf16* __restrict__ Kr,
                                                  const bf16* __restrict__ Vt,
                                                  const float* __restrict__ lp,
                                                  float* __restrict__ attn_out,
                                                  bf16* __restrict__ O) {
    __shared__ bf16 KB[2][4096];
    __shared__ float LP[2][4096];       // 64 rows x 64 f32, dbuf
    union ShU {
        struct { bf16 VB[2][4096]; bf16 P[4][1024]; } p1;   // phase 1
        float FS[4][1088];                                   // phase 2: 16 x 68 per wave
    };
    __shared__ ShU Ush;

    const int tid = threadIdx.x;
    const int lane = tid & 63, wv = tid >> 6;
    const int colL = lane & 15, grp = lane >> 4;
    // XCD swizzle: all 16 heads of a (b,qb) pair on one XCD
    const int n = blockIdx.x;
    const int x = n & 7, j = n >> 3;
    const int h = j & 15;
    const int pp = (j >> 4) * 8 + x;
    const int b = pp >> 5, qb = pp & 31;
    const int bh = b * H_ + h;
    const int q0 = qb * 64 + wv * 16;
    const int rowL = wv * 16 + colL;        // block-level q-row of this lane

    const bf16* Qbase = Qr + ((size_t)bh * S_ + q0) * HD_;
    const bf16* Kbase = Kr + (size_t)bh * S_ * HD_;
    const bf16* Vbase = Vt + (size_t)bh * HD_ * S_;
    const float* LPbase = lp + ((size_t)b * S_ + qb * 64) * S_;

    bf16x8 qf0 = *(const bf16x8*)(Qbase + (size_t)colL * HD_ + grp * 8);
    bf16x8 qf1 = *(const bf16x8*)(Qbase + (size_t)colL * HD_ + 32 + grp * 8);

    bf16* P = Ush.p1.P[wv];
    const int swz = (colL & 7) << 3;
    const int c7 = colL & 7;

    auto stageK = [&](int buf, int k0) {
#pragma unroll
        for (int i = 0; i < 2; ++i) {
            int c = i * 256 + tid;
            int row = c >> 3, sub = c & 7;
            gload_lds16(Kbase + (size_t)(k0 + row) * HD_ + ((sub ^ (row & 7)) << 3),
                        &KB[buf][(c & ~63) << 3]);
        }
    };
    auto stageV = [&](int buf, int k0) {
#pragma unroll
        for (int i = 0; i < 2; ++i) {
            int c = i * 256 + tid;
            int row = c >> 3, sub = c & 7;
            gload_lds16(Vbase + (size_t)row * S_ + k0 + ((sub ^ (row & 7)) << 3),
                        &Ush.p1.VB[buf][(c & ~63) << 3]);
        }
    };
    // lp tile: 64 rows x 64 f32 = 1024 x 16B chunks; row = c>>4, col16 = c&15
    auto stageLP = [&](int buf, int k0) {
#pragma unroll
        for (int i = 0; i < 4; ++i) {
            int c = i * 256 + tid;
            int row = c >> 4, col16 = c & 15;
            gload_lds16(LPbase + (size_t)row * S_ + k0 + ((col16 ^ (row & 7)) << 2),
                        &LP[buf][(c & ~63) << 2]);
        }
    };
    // lane's lp read address (word units) for sub-tile ct
    auto lpAddr = [&](int ct) {
        return rowL * 64 + (((ct * 4 + grp) ^ (rowL & 7)) << 2);
    };

    float ua = 0.f;
    floatx4 oT[4];
#pragma unroll
    for (int dt = 0; dt < 4; ++dt) oT[dt] = (floatx4){0.f, 0.f, 0.f, 0.f};

    // ---------------- phase 1 prologue
    stageK(0, 0);
    stageV(0, 0);
    stageLP(0, 0);
    __syncthreads();

    // ---------------- phase 1: U + O accumulation
    for (int kt = 0; kt < 32; ++kt) {
        const int k0 = kt * 64;
        const int cur = kt & 1;
        if (kt < 31) {
            stageK(cur ^ 1, k0 + 64);
            stageV(cur ^ 1, k0 + 64);
            stageLP(cur ^ 1, k0 + 64);
        }

        // QK^T from LDS
        floatx4 s[4];
#pragma unroll
        for (int ct = 0; ct < 4; ++ct) {
            const int r8 = (ct * 16 + colL) * 8;
            bf16x8 a0 = *(const bf16x8*)&KB[cur][(r8 + (grp ^ c7)) * 8];
            bf16x8 a1 = *(const bf16x8*)&KB[cur][(r8 + (grp ^ 4 ^ c7)) * 8];
            floatx4 acc = (floatx4){0.f, 0.f, 0.f, 0.f};
            acc = MFMA16(a0, qf0, acc);
            acc = MFMA16(a1, qf1, acc);
            s[ct] = acc;
        }
        // t = exp(s + lp)
#pragma unroll
        for (int ct = 0; ct < 4; ++ct) {
            float4v lv = *(const float4v*)&LP[cur][lpAddr(ct)];
            bf16x4 pw;
#pragma unroll
            for (int r = 0; r < 4; ++r) {
                float tv = __expf(s[ct][r] + lv[r]);
                ua += tv;
                pw[r] = (bf16)tv;
            }
            *(bf16x4*)&P[(colL * 64 + ct * 16 + grp * 4) ^ swz] = pw;
        }
        // PV from LDS V
#pragma unroll
        for (int ks = 0; ks < 2; ++ks) {
            bf16x8 pb = *(const bf16x8*)&P[(colL * 64 + ks * 32 + grp * 8) ^ swz];
#pragma unroll
            for (int dt = 0; dt < 4; ++dt) {
                const int r8 = (dt * 16 + colL) * 8;
                bf16x8 vf = *(const bf16x8*)&Ush.p1.VB[cur][(r8 + ((ks * 4 + grp) ^ c7)) * 8];
                oT[dt] = MFMA16(vf, pb, oT[dt]);
            }
        }
        __syncthreads();
    }

    // ---------------- U reduce + O write
    ua += __shfl_xor(ua, 16, 64);
    ua += __shfl_xor(ua, 32, 64);
    const float iu = 1.0f / ua;
#pragma unroll
    for (int dt = 0; dt < 4; ++dt) {
        bf16x4 ow;
#pragma unroll
        for (int r = 0; r < 4; ++r) ow[r] = (bf16)(oT[dt][r] * iu);
        *(bf16x4*)(O + ((size_t)b * S_ + q0 + colL) * DIM_ + h * HD_ + dt * 16 + grp * 4) = ow;
    }

    // ---------------- phase 2 prologue (FS aliases V/P space — safe after barrier)
    __syncthreads();
    stageK(0, 0);
    stageLP(0, 0);
    __syncthreads();

    // ---------------- phase 2: recompute, write attn = exp(s+lp)*invU, 256B stores
    const float* Aout = attn_out + (size_t)bh * S_ * S_;
    for (int kt = 0; kt < 32; ++kt) {
        const int k0 = kt * 64;
        const int cur = kt & 1;
        if (kt < 31) {
            stageK(cur ^ 1, k0 + 64);
            stageLP(cur ^ 1, k0 + 64);
        }

        floatx4 s[4];
#pragma unroll
        for (int ct = 0; ct < 4; ++ct) {
            const int r8 = (ct * 16 + colL) * 8;
            bf16x8 a0 = *(const bf16x8*)&KB[cur][(r8 + (grp ^ c7)) * 8];
            bf16x8 a1 = *(const bf16x8*)&KB[cur][(r8 + (grp ^ 4 ^ c7)) * 8];
            floatx4 acc = (floatx4){0.f, 0.f, 0.f, 0.f};
            acc = MFMA16(a0, qf0, acc);
            acc = MFMA16(a1, qf1, acc);
            s[ct] = acc;
        }
        // stage f32 tile into wave-private LDS (row = q-in-wave, col = k-in-tile)
#pragma unroll
        for (int ct = 0; ct < 4; ++ct) {
            float4v lv = *(const float4v*)&LP[cur][lpAddr(ct)];
            float4v o;
#pragma unroll
            for (int r = 0; r < 4; ++r)
                o[r] = __expf(s[ct][r] + lv[r]) * iu;
            *(float4v*)&Ush.FS[wv][colL * 68 + ct * 16 + grp * 4] = o;
        }
        // transposed read-out: 4 rows x 256B contiguous per instruction
#pragma unroll
        for (int it = 0; it < 4; ++it) {
            const int row = it * 4 + grp;
            float4v v = *(const float4v*)&Ush.FS[wv][row * 68 + colL * 4];
            *(float4v*)(Aout + (size_t)(q0 + row) * S_ + k0 + colL * 4) = v;
        }
        __syncthreads();
    }
}

// ---------------------------------------------------------------- launch
extern "C" void kernel_launch(void* const* d_in, const int* in_sizes, int n_in,
                              void* d_out, int out_size, void* d_ws, size_t ws_size,
                              hipStream_t stream) {
    const float* q_x   = (const float*)d_in[0];
    const float* kv_x  = (const float*)d_in[1];
    const float* q_fr  = (const float*)d_in[2];
    const float* k_fr  = (const float*)d_in[3];
    const float* maskp = (const float*)d_in[4];
    const float* prior = (const float*)d_in[5];
    const float* Wq    = (const float*)d_in[6];
    const float* Wkv   = (const float*)d_in[7];
    const float* Wproj = (const float*)d_in[8];
    const float* bproj = (const float*)d_in[9];

    float* out_x    = (float*)d_out;                       // (B,S,DIM)
    float* out_attn = out_x + (size_t)B_ * S_ * DIM_;      // (B,H,S,S)

    char* w = (char*)d_ws;
    bf16* qx_b  = (bf16*)(w + (size_t)0);          //  8 MiB
    bf16* kvx_b = (bf16*)(w + ((size_t)8  << 20)); //  8 MiB
    bf16* wq_b  = (bf16*)(w + ((size_t)16 << 20)); //  2 MiB
    bf16* wkv_b = (bf16*)(w + ((size_t)18 << 20)); //  4 MiB
    bf16* wpj_b = (bf16*)(w + ((size_t)22 << 20)); //  2 MiB
    bf16* qp    = (bf16*)(w + ((size_t)24 << 20)); //  8 MiB  (B,S,DIM)
    bf16* kvp   = (bf16*)(w + ((size_t)32 << 20)); // 16 MiB  (B,S,2*DIM)
    bf16* qr    = (bf16*)(w + ((size_t)48 << 20)); //  8 MiB  (B,H,S,HD)
    bf16* kr    = (bf16*)(w + ((size_t)56 << 20)); //  8 MiB
    bf16* vt    = (bf16*)(w + ((size_t)64 << 20)); //  8 MiB  (B,H,HD,S)
    bf16* ob    = (bf16*)(w + ((size_t)72 << 20)); //  8 MiB  (B,S,DIM)
    float* lpb  = (float*)(w + ((size_t)96 << 20)); // 32 MiB  (B,S,S) f32

    // f32 -> bf16 conversions + lp precompute
    cvt_kernel<<<4096, 256, 0, stream>>>(q_x,   qx_b,  1048576);
    cvt_kernel<<<4096, 256, 0, stream>>>(kv_x,  kvx_b, 1048576);
    cvt_kernel<<<1024, 256, 0, stream>>>(Wq,    wq_b,   262144);
    cvt_kernel<<<2048, 256, 0, stream>>>(Wkv,   wkv_b,  524288);
    cvt_kernel<<<1024, 256, 0, stream>>>(Wproj, wpj_b,  262144);
    lp_kernel<<<8192, 256, 0, stream>>>(maskp, prior, lpb, 2097152);

    // projections
    gemm_bt<0, 0><<<dim3(8, 32),  256, 0, stream>>>(qx_b,  wq_b,  qp,  nullptr, 4096, 1024, 1024);
    gemm_bt<0, 0><<<dim3(16, 32), 256, 0, stream>>>(kvx_b, wkv_b, kvp, nullptr, 4096, 2048, 1024);

    // RoPE + layout
    rope_kernel<<<2048, 256, 0, stream>>>(qp,  q_fr, qr, 1024, SCALE_);
    rope_kernel<<<2048, 256, 0, stream>>>(kvp, k_fr, kr, 2048, 1.0f);
    vtrans_kernel<<<1024, 256, 0, stream>>>(kvp, vt);

    // fused attention: O + attn in one kernel (XCD-swizzled grid)
    attn_fused<<<1024, 256, 0, stream>>>(qr, kr, vt, lpb, out_attn, ob);

    // output projection
    gemm_bt<1, 1><<<dim3(8, 32), 256, 0, stream>>>(ob, wpj_b, out_x, bproj, 4096, 1024, 1024);
}